// Round 11
// baseline (743.290 us; speedup 1.0000x reference)
//
#include <hip/hip_runtime.h>
#include <hip/hip_bf16.h>

// B=64, T=60 (40 enc + 20 dec), H=512, E=512, V=32000. fp32 I/O.
// r11 structure (overlap path, ws >= ~65.6MB):
//   1) prep_new (small): builds xs[3840][1024] bf16 (feature cols + embedding
//      gather), cvt W_ih -> wih bf16, zeroes flags[0..127]. ~10us.
//   2) mega (ONE dispatch, 3268 blocks, 4 roles; producers get lowest IDs so
//      the first 512 resident blocks (2/CU) are exactly xproj+LSTM):
//        0..479    xproj tiles: Xp = xs @ wih^T + b (pure-bf16 gload_lds
//                  staging; enc tiles skip k<512). C-write = agent
//                  write-through stores; drain; xdone[by]++ and xtotal++.
//        480..511  persistent LSTM (r7 body): Xp reads are now L2-bypass
//                  atomic loads; waits xdone[0]==16 once after W-staging;
//                  per-step confirms row (t+2)>>1 on lane 255 INSIDE the
//                  existing barrier-spin (overlapped, no added latency).
//        512..767  cvt W_lin -> wbf (write-through u64 stores; drain;
//                  wdone++). Done by ~80us, needed at ~235us.
//        768..3267 gemm_out consumers (r9-proven): poll epoch | wdone |
//                  xtotal on lanes 0|64|128, then per-k0 A bypass staging +
//                  swizzled gload_lds B. xtotal also guarantees xs/wih in
//                  d_out's tail are dead before consumers overwrite out.
//   Fallback (ws small): prep_old + mega grid=512 (xs=null: xproj blocks
//   return, LSTM skips polls) + gemm_out<false>.

typedef short bf16x8 __attribute__((ext_vector_type(8)));
typedef float f32x4 __attribute__((ext_vector_type(4)));

__device__ inline short f2bf(float f) {
    unsigned u = __float_as_uint(f);
    unsigned r = (u + 0x7fffu + ((u >> 16) & 1u)) >> 16;   // RNE
    return (short)r;
}
__device__ inline int4 ld8_f32_to_bf16(const float* __restrict__ g) {
    float4 a = *(const float4*)g;
    float4 b = *(const float4*)(g + 4);
    union { short s[8]; int4 v; } u;
    u.s[0] = f2bf(a.x); u.s[1] = f2bf(a.y); u.s[2] = f2bf(a.z); u.s[3] = f2bf(a.w);
    u.s[4] = f2bf(b.x); u.s[5] = f2bf(b.y); u.s[6] = f2bf(b.z); u.s[7] = f2bf(b.w);
    return u.v;
}
__device__ inline float sig_fast(float x) {
    return __builtin_amdgcn_rcpf(1.0f + __expf(-x));
}
__device__ inline float tanh_fast(float x) {
    return 1.0f - 2.0f * __builtin_amdgcn_rcpf(1.0f + __expf(2.0f * x));
}
__device__ inline void gload_lds16(const void* g, void* l) {
    __builtin_amdgcn_global_load_lds(
        (const __attribute__((address_space(1))) void*)g,
        (__attribute__((address_space(3))) void*)l, 16, 0, 0);
}

#define NXPROJ 480
#define NLSTM  32
#define NCVT   256
#define NCONS  2500
#define LSTM_BASE  480
#define CVT_BASE   512
#define CONS_BASE  768
// flags: [0..31] lstm step; [32] epoch; [33..62] xdone rows 0..29;
//        [63] wdone; [64] xtotal. (128 dwords zeroed by prep.)

// ---------------------------------------------------------------------------
// prep_new: xs build (feature cols 512.. + embedding gather for dec rows),
// W_ih cvt, zero flags. Grid-stride streaming, no LDS.
// ---------------------------------------------------------------------------
__global__ __launch_bounds__(256) void prep_new(
    const float* __restrict__ feature,    // [64][60][512]
    const int*   __restrict__ captions,   // [64][20]
    const float* __restrict__ embedding,  // [32000][512]
    const float* __restrict__ W_ih,       // [2048][1024]
    short* __restrict__ xs,               // [3840][1024] bf16
    short* __restrict__ wih,              // [2048][1024] bf16
    unsigned* __restrict__ flags)
{
    const int tid = threadIdx.x;
    if (blockIdx.x == 0 && tid < 128) flags[tid] = 0;

    const int NF = 3840 * 64;
    const int NE = 1280 * 64;
    const int NW = 2048 * 128;
    const int total = NF + NE + NW;
    const int stride = gridDim.x * 256;

    for (int idx = blockIdx.x * 256 + tid; idx < total; idx += stride) {
        if (idx < NF) {
            int row = idx >> 6, c8 = (idx & 63) * 8;
            int t = row >> 6, b = row & 63;
            *(int4*)&xs[(size_t)row * 1024 + 512 + c8] =
                ld8_f32_to_bf16(&feature[(size_t)(b * 60 + t) * 512 + c8]);
        } else if (idx < NF + NE) {
            int j = idx - NF;
            int r = j >> 6, c8 = (j & 63) * 8;
            int t = 40 + (r >> 6), b = r & 63;
            int tok = captions[b * 20 + (t - 40)];
            *(int4*)&xs[(size_t)(2560 + r) * 1024 + c8] =
                ld8_f32_to_bf16(&embedding[(size_t)tok * 512 + c8]);
        } else {
            int j = idx - NF - NE;
            *(int4*)&wih[(size_t)j * 8] = ld8_f32_to_bf16(&W_ih[(size_t)j * 8]);
        }
    }
}

// ---------------------------------------------------------------------------
// prep_old (fallback only — r9 verbatim minus cvt): xproj tiles + flag zero.
// ---------------------------------------------------------------------------
__global__ __launch_bounds__(256) void prep_old(
    const float* __restrict__ feature,
    const int*   __restrict__ captions,
    const float* __restrict__ embedding,
    const float* __restrict__ W_ih,
    const float* __restrict__ b_ih,
    const float* __restrict__ b_hh,
    float* __restrict__ Xp,
    unsigned* __restrict__ flags)
{
    const int blk = blockIdx.x;
    const int tid = threadIdx.x;

    if (blk == 480) {
        if (tid < 128) flags[tid] = 0;
        return;
    }

    __shared__ __align__(16) short Al[128 * 72];
    __shared__ __align__(16) short Bl[128 * 72];
    const int wave = tid >> 6, lane = tid & 63;
    const int quad = lane >> 4, l16 = lane & 15;
    const int bx = blk & 15, by = blk >> 4;
    const int m0 = by * 128;
    const int n0 = bx * 128;
    const int wm = (wave >> 1) * 64, wn = (wave & 1) * 64;
    const int sr = tid >> 3;
    const int sc = (tid & 7) * 8;
    const bool dec = (by >= 20);
    const int kstart = dec ? 0 : 512;

    f32x4 acc[4][4] = {};

    for (int k0 = kstart; k0 < 1024; k0 += 64) {
        const int j = k0 + sc;
#pragma unroll
        for (int p = 0; p < 4; ++p) {
            int r = sr + p * 32;
            int row = m0 + r;
            int t = row >> 6, b = row & 63;
            int4 val;
            if (dec && j < 512) {
                int tok = captions[b * 20 + (t - 40)];
                val = ld8_f32_to_bf16(&embedding[(size_t)tok * 512 + j]);
            } else {
                val = ld8_f32_to_bf16(&feature[(size_t)(b * 60 + t) * 512 + (j - 512)]);
            }
            *(int4*)&Al[r * 72 + sc] = val;
            *(int4*)&Bl[r * 72 + sc] = ld8_f32_to_bf16(&W_ih[(size_t)(n0 + r) * 1024 + j]);
        }
        __syncthreads();
#pragma unroll
        for (int kk = 0; kk < 64; kk += 32) {
            bf16x8 af[4], bg[4];
#pragma unroll
            for (int i = 0; i < 4; ++i)
                af[i] = *(const bf16x8*)&Al[(wm + i * 16 + l16) * 72 + kk + quad * 8];
#pragma unroll
            for (int jj = 0; jj < 4; ++jj)
                bg[jj] = *(const bf16x8*)&Bl[(wn + jj * 16 + l16) * 72 + kk + quad * 8];
#pragma unroll
            for (int i = 0; i < 4; ++i)
#pragma unroll
                for (int jj = 0; jj < 4; ++jj)
                    acc[i][jj] = __builtin_amdgcn_mfma_f32_16x16x32_bf16(
                        af[i], bg[jj], acc[i][jj], 0, 0, 0);
        }
        __syncthreads();
    }

#pragma unroll
    for (int jj = 0; jj < 4; ++jj) {
        int n = n0 + wn + jj * 16 + l16;
        float bv = b_ih[n] + b_hh[n];
#pragma unroll
        for (int i = 0; i < 4; ++i) {
            int mbase = m0 + wm + i * 16 + quad * 4;
#pragma unroll
            for (int r = 0; r < 4; ++r)
                Xp[(size_t)(mbase + r) * 2048 + n] = acc[i][jj][r] + bv;
        }
    }
}

// ---------------------------------------------------------------------------
// Standalone GEMM2 (fallback): A slice-major bf16; C rows permuted.
// ---------------------------------------------------------------------------
template <bool BF16B>
__global__ __launch_bounds__(256) void gemm_out(
    const short* __restrict__ A,
    const void*  __restrict__ Wv,
    const float* __restrict__ bias,
    float* __restrict__ C,
    int M, int N, int K)
{
    __shared__ __align__(16) short Al[128 * 72];
    __shared__ __align__(16) short Bl[128 * 72];
    const int tid  = threadIdx.x;
    const int wave = tid >> 6, lane = tid & 63;
    const int quad = lane >> 4, l16 = lane & 15;
    const int m0 = blockIdx.y * 128;
    const int n0 = blockIdx.x * 128;
    const int wm = (wave >> 1) * 64, wn = (wave & 1) * 64;
    const int sr = tid >> 3;
    const int sc = (tid & 7) * 8;

    f32x4 acc[4][4] = {};

    for (int k0 = 0; k0 < K; k0 += 64) {
#pragma unroll
        for (int p = 0; p < 4; ++p) {
            int r = sr + p * 32;
            int am = m0 + r;
            am = (am < M) ? am : (M - 1);
            *(int4*)&Al[r * 72 + sc] = *(const int4*)&A[(size_t)am * K + k0 + sc];
            if (BF16B)
                *(int4*)&Bl[r * 72 + sc] =
                    *(const int4*)&((const short*)Wv)[(size_t)(n0 + r) * K + k0 + sc];
            else
                *(int4*)&Bl[r * 72 + sc] =
                    ld8_f32_to_bf16(&((const float*)Wv)[(size_t)(n0 + r) * K + k0 + sc]);
        }
        __syncthreads();
#pragma unroll
        for (int kk = 0; kk < 64; kk += 32) {
            bf16x8 af[4], bg[4];
#pragma unroll
            for (int i = 0; i < 4; ++i)
                af[i] = *(const bf16x8*)&Al[(wm + i * 16 + l16) * 72 + kk + quad * 8];
#pragma unroll
            for (int jj = 0; jj < 4; ++jj)
                bg[jj] = *(const bf16x8*)&Bl[(wn + jj * 16 + l16) * 72 + kk + quad * 8];
#pragma unroll
            for (int i = 0; i < 4; ++i)
#pragma unroll
                for (int jj = 0; jj < 4; ++jj)
                    acc[i][jj] = __builtin_amdgcn_mfma_f32_16x16x32_bf16(
                        af[i], bg[jj], acc[i][jj], 0, 0, 0);
        }
        __syncthreads();
    }

#pragma unroll
    for (int jj = 0; jj < 4; ++jj) {
        int n = n0 + wn + jj * 16 + l16;
        float bv = bias[n];
#pragma unroll
        for (int i = 0; i < 4; ++i) {
            int mbase = m0 + wm + i * 16 + quad * 4;
#pragma unroll
            for (int r = 0; r < 4; ++r) {
                int ar = mbase + r;
                if (ar < M) {
                    int crow = (ar & 63) * 19 + (ar >> 6);
                    C[(size_t)crow * N + n] = acc[i][jj][r] + bv;
                }
            }
        }
    }
}

// ---------------------------------------------------------------------------
// MEGA v3: 4 roles. xproj(0..479) | LSTM(480..511) | cvt(512..767) |
// consumers(768..3267). 66KB smem -> 2 blocks/CU.
// ---------------------------------------------------------------------------
__global__ __launch_bounds__(256, 1) void mega(
    const short* __restrict__ xs,     // [3840][1024] bf16 (null = fallback)
    const short* __restrict__ wih,    // [2048][1024] bf16
    const float* __restrict__ b_ih,
    const float* __restrict__ b_hh,
    float* __restrict__ Xp,           // [3840][2048] fp32
    const float* __restrict__ W_hh,   // [2048][512] fp32
    unsigned long long* __restrict__ hbuf,  // [2][64][512] bf16 ping-pong
    unsigned long long* __restrict__ dec_h, // [(t-40)*64+b][512] bf16 as u64
    unsigned* __restrict__ flags,
    const float* __restrict__ W_lin,  // [32000][512] fp32
    short* __restrict__ wbf,          // [32000][512] bf16 (written in-kernel)
    const float* __restrict__ b_lin,  // [32000]
    float* __restrict__ out)          // [1216][32000] fp32
{
    __shared__ __align__(16) char smem[67584];
    const int tid  = threadIdx.x;
    const int wave = tid >> 6, lane = tid & 63;
    const int quad = lane >> 4, l16 = lane & 15;

    if (blockIdx.x < NXPROJ) {
        // ===================== xproj tile ==================================
        if (!xs) return;
        short* Al = (short*)smem;              // 128 x 64 (16 KB)
        short* Bl = (short*)(smem + 16384);    // 128 x 64 (16 KB)
        const int by = blockIdx.x >> 4;        // 0..29
        const int n0 = (blockIdx.x & 15) * 128;
        const int m0 = by * 128;
        const int wm = (wave >> 1) * 64, wn = (wave & 1) * 64;
        const int kstart = (by >= 20) ? 0 : 512;

        const char* Ab = (const char*)xs;
        const char* Wb = (const char*)wih;
        char* AlB = (char*)Al;
        char* BlB = (char*)Bl;

        f32x4 acc[4][4] = {};

        for (int k0 = kstart; k0 < 1024; k0 += 64) {
#pragma unroll
            for (int p = 0; p < 4; ++p) {
                int row = p * 32 + wave * 8 + (lane >> 3);
                int ss  = ((lane & 7) ^ (row & 7)) << 4;
                gload_lds16(Ab + (size_t)(m0 + row) * 2048 + k0 * 2 + ss,
                            AlB + p * 4096 + wave * 1024);
                gload_lds16(Wb + (size_t)(n0 + row) * 2048 + k0 * 2 + ss,
                            BlB + p * 4096 + wave * 1024);
            }
            __syncthreads();
#pragma unroll
            for (int kk = 0; kk < 64; kk += 32) {
                bf16x8 af[4], bg[4];
                const int s_ = (kk >> 3) + quad;
#pragma unroll
                for (int i = 0; i < 4; ++i) {
                    int rw = wm + i * 16 + l16;
                    af[i] = *(const bf16x8*)&Al[rw * 64 + ((s_ ^ (rw & 7)) << 3)];
                }
#pragma unroll
                for (int jj = 0; jj < 4; ++jj) {
                    int rw = wn + jj * 16 + l16;
                    bg[jj] = *(const bf16x8*)&Bl[rw * 64 + ((s_ ^ (rw & 7)) << 3)];
                }
#pragma unroll
                for (int i = 0; i < 4; ++i)
#pragma unroll
                    for (int jj = 0; jj < 4; ++jj)
                        acc[i][jj] = __builtin_amdgcn_mfma_f32_16x16x32_bf16(
                            af[i], bg[jj], acc[i][jj], 0, 0, 0);
            }
            __syncthreads();
        }

        // C-write: agent write-through stores (LSTM reads via bypass loads)
#pragma unroll
        for (int jj = 0; jj < 4; ++jj) {
            int n = n0 + wn + jj * 16 + l16;
            float bv = b_ih[n] + b_hh[n];
#pragma unroll
            for (int i = 0; i < 4; ++i) {
                int mbase = m0 + wm + i * 16 + quad * 4;
#pragma unroll
                for (int r = 0; r < 4; ++r)
                    __hip_atomic_store(&Xp[(size_t)(mbase + r) * 2048 + n],
                                       acc[i][jj][r] + bv,
                                       __ATOMIC_RELAXED, __HIP_MEMORY_SCOPE_AGENT);
            }
        }
        __syncthreads();   // drain vmcnt -> all stores at coherence point
        if (tid == 0) {
            __hip_atomic_fetch_add(&flags[33 + by], 1u,
                                   __ATOMIC_RELAXED, __HIP_MEMORY_SCOPE_AGENT);
            __hip_atomic_fetch_add(&flags[64], 1u,
                                   __ATOMIC_RELAXED, __HIP_MEMORY_SCOPE_AGENT);
        }
        return;
    }

    if (blockIdx.x < CVT_BASE) {
        // ===================== LSTM (r7 body) ==============================
        const int lid = blockIdx.x - LSTM_BASE;    // 0..31
        short* Wl  = (short*)smem;                 // 64 KB, swizzled
        short* Htb = (short*)(smem + 65536);       // 2 KB
        const int nb = lid * 16;
        const int swz = (l16 & 7) << 3;

#pragma unroll
        for (int it = 0; it < 16; ++it) {
            int rr = (tid >> 6) + it * 4;
            int k  = (tid & 63) * 8;
            int s = rr >> 4, col = rr & 15;
            *(int4*)&Wl[(rr * 512 + k) ^ ((rr & 7) << 3)] =
                ld8_f32_to_bf16(&W_hh[(size_t)(s * 512 + nb + col) * 512 + k]);
        }
        float creg[4] = {0.f, 0.f, 0.f, 0.f};

        // wait for Xp row 0 (16 tiles) — overlaps with W staging above
        if (xs) {
            int guard = 0;
            while (__hip_atomic_load(&flags[33], __ATOMIC_RELAXED,
                                     __HIP_MEMORY_SCOPE_AGENT) < 16u
                   && guard < (1 << 16)) {
                __builtin_amdgcn_s_sleep(1);
                ++guard;
            }
        }

        const int n = nb + l16;
        float xg[4][4];
#pragma unroll
        for (int r = 0; r < 4; ++r) {
            const float* xr = Xp + (size_t)(wave * 16 + quad * 4 + r) * 2048;
            xg[r][0] = __hip_atomic_load(&xr[n], __ATOMIC_RELAXED, __HIP_MEMORY_SCOPE_AGENT);
            xg[r][1] = __hip_atomic_load(&xr[512 + n], __ATOMIC_RELAXED, __HIP_MEMORY_SCOPE_AGENT);
            xg[r][2] = __hip_atomic_load(&xr[1024 + n], __ATOMIC_RELAXED, __HIP_MEMORY_SCOPE_AGENT);
            xg[r][3] = __hip_atomic_load(&xr[1536 + n], __ATOMIC_RELAXED, __HIP_MEMORY_SCOPE_AGENT);
        }
        __syncthreads();

        for (int t = 0; t < 59; ++t) {
            f32x4 acc[4] = {};
            if (t > 0) {
                const unsigned long long* hrow =
                    hbuf + ((size_t)((t & 1) ^ 1) << 13)
                         + (size_t)(wave * 16 + l16) * 128 + quad * 2;
                union { unsigned long long q[2]; bf16x8 v; } hu[16];
#pragma unroll
                for (int kk = 0; kk < 16; ++kk) {
                    hu[kk].q[0] = __hip_atomic_load(&hrow[kk * 8],
                                     __ATOMIC_RELAXED, __HIP_MEMORY_SCOPE_AGENT);
                    hu[kk].q[1] = __hip_atomic_load(&hrow[kk * 8 + 1],
                                     __ATOMIC_RELAXED, __HIP_MEMORY_SCOPE_AGENT);
                }
                __builtin_amdgcn_sched_barrier(0);
#pragma unroll
                for (int kk = 0; kk < 16; ++kk) {
#pragma unroll
                    for (int s = 0; s < 4; ++s) {
                        bf16x8 bg = *(const bf16x8*)
                            &Wl[((s * 16 + l16) * 512 + kk * 32 + quad * 8) ^ swz];
                        acc[s] = __builtin_amdgcn_mfma_f32_16x16x32_bf16(
                            hu[kk].v, bg, acc[s], 0, 0, 0);
                    }
                }
            }
#pragma unroll
            for (int r = 0; r < 4; ++r) {
                float iv = acc[0][r] + xg[r][0];
                float fv = acc[1][r] + xg[r][1];
                float gv = acc[2][r] + xg[r][2];
                float ov = acc[3][r] + xg[r][3];
                float cn = sig_fast(fv) * creg[r] + sig_fast(iv) * tanh_fast(gv);
                float hn = sig_fast(ov) * tanh_fast(cn);
                creg[r] = cn;
                Htb[(wave << 8) + ((quad * 4 + r) << 4) + l16] = f2bf(hn);
            }
            asm volatile("s_waitcnt lgkmcnt(0)" ::: "memory");
            unsigned long long* hout64 = hbuf + ((size_t)(t & 1) << 13);
            {
                int row = lane >> 2, qp = lane & 3;
                unsigned long long v =
                    *(const unsigned long long*)&Htb[(wave << 8) + (row << 4) + qp * 4];
                int m = wave * 16 + row;
                __hip_atomic_store(&hout64[m * 128 + (nb >> 2) + qp], v,
                                   __ATOMIC_RELAXED, __HIP_MEMORY_SCOPE_AGENT);
                if (t >= 40)
                    __hip_atomic_store(
                        &dec_h[(size_t)((t - 40) * 64 + m) * 128 + (nb >> 2) + qp], v,
                        __ATOMIC_RELAXED, __HIP_MEMORY_SCOPE_AGENT);
            }
            if (t < 58) {
                // Xp prefetch for t+1 (row (t+1)>>1 confirmed at step t-1 /
                // upfront): bypass loads, overlap the store-ack drain.
                float xn_[4][4];
                const float* xt = Xp + (size_t)(t + 1) * 131072;
#pragma unroll
                for (int r = 0; r < 4; ++r) {
                    const float* xr = xt + (size_t)(wave * 16 + quad * 4 + r) * 2048;
                    xn_[r][0] = __hip_atomic_load(&xr[n], __ATOMIC_RELAXED, __HIP_MEMORY_SCOPE_AGENT);
                    xn_[r][1] = __hip_atomic_load(&xr[512 + n], __ATOMIC_RELAXED, __HIP_MEMORY_SCOPE_AGENT);
                    xn_[r][2] = __hip_atomic_load(&xr[1024 + n], __ATOMIC_RELAXED, __HIP_MEMORY_SCOPE_AGENT);
                    xn_[r][3] = __hip_atomic_load(&xr[1536 + n], __ATOMIC_RELAXED, __HIP_MEMORY_SCOPE_AGENT);
                }
                __syncthreads();   // drains vmcnt(0): h+dec_h at coherence pt
                if (tid == 0)
                    __hip_atomic_store(&flags[lid], (unsigned)(t + 1),
                                       __ATOMIC_RELAXED, __HIP_MEMORY_SCOPE_AGENT);
                if (tid < NLSTM) {
                    int guard = 0;
                    while (__hip_atomic_load(&flags[tid], __ATOMIC_RELAXED,
                                             __HIP_MEMORY_SCOPE_AGENT) < (unsigned)(t + 1)
                           && guard < (1 << 16)) {
                        __builtin_amdgcn_s_sleep(1);
                        ++guard;
                    }
                } else if (xs && tid == 255) {
                    // confirm Xp row (t+2)>>1 for NEXT step's prefetch —
                    // overlapped with the flag spin (same RTT window)
                    int pr = (t + 2) >> 1; pr = (pr < 29) ? pr : 29;
                    int guard = 0;
                    while (__hip_atomic_load(&flags[33 + pr], __ATOMIC_RELAXED,
                                             __HIP_MEMORY_SCOPE_AGENT) < 16u
                           && guard < (1 << 16)) {
                        __builtin_amdgcn_s_sleep(1);
                        ++guard;
                    }
                }
                __syncthreads();
                if (lid == 0 && tid == 0)
                    __hip_atomic_store(&flags[32], (unsigned)(t + 1),
                                       __ATOMIC_RELAXED, __HIP_MEMORY_SCOPE_AGENT);
#pragma unroll
                for (int r = 0; r < 4; ++r)
#pragma unroll
                    for (int g = 0; g < 4; ++g)
                        xg[r][g] = xn_[r][g];
            }
        }
        __syncthreads();           // drains t=58 dec_h/h stores
        if (tid == 0)
            __hip_atomic_store(&flags[lid], 59u,
                               __ATOMIC_RELAXED, __HIP_MEMORY_SCOPE_AGENT);
        if (lid == 0) {
            if (tid < NLSTM) {
                int guard = 0;
                while (__hip_atomic_load(&flags[tid], __ATOMIC_RELAXED,
                                         __HIP_MEMORY_SCOPE_AGENT) < 59u
                       && guard < (1 << 16)) {
                    __builtin_amdgcn_s_sleep(1);
                    ++guard;
                }
            }
            __syncthreads();
            if (tid == 0)
                __hip_atomic_store(&flags[32], 59u,
                                   __ATOMIC_RELAXED, __HIP_MEMORY_SCOPE_AGENT);
        }
        return;
    }

    if (blockIdx.x < CONS_BASE) {
        // ===================== W_lin cvt ===================================
        if (!xs) return;
        const int cb = blockIdx.x - CVT_BASE;      // 0..255
        for (int idx = cb * 256 + tid; idx < 2048000; idx += NCVT * 256) {
            union { int4 v4; unsigned long long q[2]; } u;
            u.v4 = ld8_f32_to_bf16(&W_lin[(size_t)idx * 8]);
            unsigned long long* d = (unsigned long long*)&wbf[(size_t)idx * 8];
            __hip_atomic_store(&d[0], u.q[0],
                               __ATOMIC_RELAXED, __HIP_MEMORY_SCOPE_AGENT);
            __hip_atomic_store(&d[1], u.q[1],
                               __ATOMIC_RELAXED, __HIP_MEMORY_SCOPE_AGENT);
        }
        __syncthreads();   // drain -> stores at coherence point
        if (tid == 0)
            __hip_atomic_fetch_add(&flags[63], 1u,
                                   __ATOMIC_RELAXED, __HIP_MEMORY_SCOPE_AGENT);
        return;
    }

    // ===================== consumer: one 128x128 tile of out ===============
    short* Al = (short*)smem;                      // 128 x 72 padded (A)
    short* Bl = (short*)(smem + 18432);            // 128 x 64 swizzled (B)
    const int cid = blockIdx.x - CONS_BASE;
    const int n0 = (cid % 250) * 128;
    const int mt = cid / 250;
    const int m0 = mt * 128;
    const int M = 1216;
    const int wm = (wave >> 1) * 64, wn = (wave & 1) * 64;
    const int sr = tid >> 3;
    const int sc = (tid & 7) * 8;
    int maxa = m0 + 127; maxa = (maxa < M - 1) ? maxa : (M - 1);
    const unsigned v = 41u + (unsigned)(maxa >> 6);

    // parallel polls: epoch | wdone | xtotal (xtotal also guards d_out tail)
    if (tid == 0) {
        int guard = 0;
        while (__hip_atomic_load(&flags[32], __ATOMIC_RELAXED,
                                 __HIP_MEMORY_SCOPE_AGENT) < v
               && guard < (1 << 14)) {
            __builtin_amdgcn_s_sleep(64);
            ++guard;
        }
    } else if (tid == 64) {
        int guard = 0;
        while (__hip_atomic_load(&flags[63], __ATOMIC_RELAXED,
                                 __HIP_MEMORY_SCOPE_AGENT) < (unsigned)NCVT
               && guard < (1 << 14)) {
            __builtin_amdgcn_s_sleep(64);
            ++guard;
        }
    } else if (tid == 128) {
        int guard = 0;
        while (__hip_atomic_load(&flags[64], __ATOMIC_RELAXED,
                                 __HIP_MEMORY_SCOPE_AGENT) < (unsigned)NXPROJ
               && guard < (1 << 14)) {
            __builtin_amdgcn_s_sleep(64);
            ++guard;
        }
    }
    __syncthreads();

    f32x4 acc[4][4] = {};
    const char* Wb = (const char*)wbf;
    char* BlB = (char*)Bl;

    for (int k0 = 0; k0 < 512; k0 += 64) {
#pragma unroll
        for (int p = 0; p < 4; ++p) {
            int r = sr + p * 32;
            int ar = m0 + r; ar = (ar < M) ? ar : (M - 1);
            size_t qi = (size_t)ar * 128 + ((k0 + sc) >> 2);
            union { unsigned long long q[2]; int4 v4; } u;
            u.q[0] = __hip_atomic_load(&dec_h[qi],
                         __ATOMIC_RELAXED, __HIP_MEMORY_SCOPE_AGENT);
            u.q[1] = __hip_atomic_load(&dec_h[qi + 1],
                         __ATOMIC_RELAXED, __HIP_MEMORY_SCOPE_AGENT);
            *(int4*)&Al[r * 72 + sc] = u.v4;
        }
#pragma unroll
        for (int p = 0; p < 4; ++p) {
            int row = p * 32 + wave * 8 + (lane >> 3);
            int ss  = ((lane & 7) ^ (row & 7)) << 4;
            gload_lds16(Wb + (size_t)(n0 + row) * 1024 + k0 * 2 + ss,
                        BlB + p * 4096 + wave * 1024);
        }
        __syncthreads();
#pragma unroll
        for (int kk = 0; kk < 64; kk += 32) {
            bf16x8 af[4], bg[4];
            const int s_ = (kk >> 3) + quad;
#pragma unroll
            for (int i = 0; i < 4; ++i)
                af[i] = *(const bf16x8*)&Al[(wm + i * 16 + l16) * 72 + kk + quad * 8];
#pragma unroll
            for (int jj = 0; jj < 4; ++jj) {
                int rw = wn + jj * 16 + l16;
                bg[jj] = *(const bf16x8*)&Bl[rw * 64 + ((s_ ^ (rw & 7)) << 3)];
            }
#pragma unroll
            for (int i = 0; i < 4; ++i)
#pragma unroll
                for (int jj = 0; jj < 4; ++jj)
                    acc[i][jj] = __builtin_amdgcn_mfma_f32_16x16x32_bf16(
                        af[i], bg[jj], acc[i][jj], 0, 0, 0);
        }
        __syncthreads();
    }

#pragma unroll
    for (int jj = 0; jj < 4; ++jj) {
        int n = n0 + wn + jj * 16 + l16;
        float bv = b_lin[n];
#pragma unroll
        for (int i = 0; i < 4; ++i) {
            int mbase = m0 + wm + i * 16 + quad * 4;
#pragma unroll
            for (int r = 0; r < 4; ++r) {
                int ar = mbase + r;
                if (ar < M) {
                    int crow = (ar & 63) * 19 + (ar >> 6);   // b*19 + dec
                    out[(size_t)crow * 32000 + n] = acc[i][jj][r] + bv;
                }
            }
        }
    }
}

// ---------------------------------------------------------------------------
extern "C" void kernel_launch(void* const* d_in, const int* in_sizes, int n_in,
                              void* d_out, int out_size, void* d_ws, size_t ws_size,
                              hipStream_t stream)
{
    (void)in_sizes; (void)n_in; (void)out_size;
    const float* feature   = (const float*)d_in[0];
    const int*   captions  = (const int*)d_in[1];
    const float* embedding = (const float*)d_in[2];
    const float* W_ih      = (const float*)d_in[3];
    const float* W_hh      = (const float*)d_in[4];
    const float* b_ih      = (const float*)d_in[5];
    const float* b_hh      = (const float*)d_in[6];
    const float* W_lin     = (const float*)d_in[7];
    const float* b_lin     = (const float*)d_in[8];
    float* out = (float*)d_out;

    // ws layout
    char* ws = (char*)d_ws;
    unsigned long long* hbuf = (unsigned long long*)(ws);          // 131,072 B
    unsigned long long* dech = (unsigned long long*)(ws + 131072); // 1,245,184 B
    unsigned* flags = (unsigned*)(ws + 1376256);                   // 512 B
    short*    wbf   = (short*)(ws + 1376768);                      // 32,768,000 B
    float*    xpws  = (float*)(ws + 34144768);                     // 31,457,280 B
    const bool bigx = ws_size >= (size_t)34144768 + 31457280;

    if (bigx) {
        // xs/wih in d_out's tail (consumed by xproj blocks before consumers
        // overwrite out — guaranteed by xtotal polling, not just timing).
        short* xs  = (short*)((char*)d_out + 143589376);   // 7,864,320 B
        short* wih = (short*)((char*)d_out + 151453696);   // 4,194,304 B
        float* Xp  = xpws;

        prep_new<<<1024, 256, 0, stream>>>(
            feature, captions, embedding, W_ih, xs, wih, flags);

        mega<<<dim3(NXPROJ + NLSTM + NCVT + NCONS), 256, 0, stream>>>(
            xs, wih, b_ih, b_hh, Xp, W_hh, hbuf, dech, flags,
            W_lin, wbf, b_lin, out);
    } else {
        // fallback: serial pipeline (xproj in prep_old, LSTM-only mega,
        // fp32-B gemm_out). Never taken when ws >= 65.6 MB.
        float* Xp = (float*)d_out;
        prep_old<<<dim3(481), 256, 0, stream>>>(
            feature, captions, embedding, W_ih, b_ih, b_hh, Xp, flags);
        mega<<<dim3(CVT_BASE), 256, 0, stream>>>(
            (const short*)nullptr, (const short*)nullptr, b_ih, b_hh, Xp,
            W_hh, hbuf, dech, flags, W_lin, (short*)nullptr, b_lin, out);
        gemm_out<false><<<dim3(250, 10), 256, 0, stream>>>(
            (const short*)dech, W_lin, b_lin, out, 1216, 32000, 512);
    }
}

// Round 12
// 672.468 us; speedup vs baseline: 1.1053x; 1.1053x over previous
//
#include <hip/hip_runtime.h>
#include <hip/hip_bf16.h>

// B=64, T=60 (40 enc + 20 dec), H=512, E=512, V=32000. fp32 I/O.
// r12 structure (overlap path, ws >= ~65.6MB) — r10 verbatim except prep:
//   1) prep_new (10304 blocks, ONE 8-elem chunk per thread — no grid-stride
//      loop): builds xs[3840][1024] bf16 (feature cols + embedding gather),
//      cvt W_ih -> wih bf16, cvt W_lin -> wbf bf16, zeroes flags.
//      r11 analysis: the looped version ran at ~650 GB/s (one 32B load in
//      flight per wave = MLP starvation, ~205us); one-chunk-per-thread is
//      the r7-proven 4.5 TB/s pattern (~30us for 131 MB).
//   2) xproj_gemm: pure-bf16 GEMM (swizzled global_load_lds), ~40us.
//   3) mega (verbatim r9/r10, measured 418us): blocks 0..31 persistent LSTM;
//      blocks 32..2531 gemm_out consumers (66KB LDS -> 2/CU, per-k0 A
//      staging, single epoch-cell poll).
//   Fallback (ws small): r9 serial pipeline.

typedef short bf16x8 __attribute__((ext_vector_type(8)));
typedef float f32x4 __attribute__((ext_vector_type(4)));

__device__ inline short f2bf(float f) {
    unsigned u = __float_as_uint(f);
    unsigned r = (u + 0x7fffu + ((u >> 16) & 1u)) >> 16;   // RNE
    return (short)r;
}
__device__ inline int4 ld8_f32_to_bf16(const float* __restrict__ g) {
    float4 a = *(const float4*)g;
    float4 b = *(const float4*)(g + 4);
    union { short s[8]; int4 v; } u;
    u.s[0] = f2bf(a.x); u.s[1] = f2bf(a.y); u.s[2] = f2bf(a.z); u.s[3] = f2bf(a.w);
    u.s[4] = f2bf(b.x); u.s[5] = f2bf(b.y); u.s[6] = f2bf(b.z); u.s[7] = f2bf(b.w);
    return u.v;
}
__device__ inline float sig_fast(float x) {
    return __builtin_amdgcn_rcpf(1.0f + __expf(-x));
}
__device__ inline float tanh_fast(float x) {
    return 1.0f - 2.0f * __builtin_amdgcn_rcpf(1.0f + __expf(2.0f * x));
}
__device__ inline void gload_lds16(const void* g, void* l) {
    __builtin_amdgcn_global_load_lds(
        (const __attribute__((address_space(1))) void*)g,
        (__attribute__((address_space(3))) void*)l, 16, 0, 0);
}

#define LSTM_BLOCKS 32

// ---------------------------------------------------------------------------
// prep_new: ONE chunk (8 elems) per thread. Sections:
//   A: xs feature cols   (NF = 3840*64)
//   B: xs embedding gather, dec rows (NE = 1280*64)
//   C: W_ih cvt          (NW = 2048*128)
//   D: W_lin cvt         (NL = 2048000)
// grid = (NF+NE+NW+NL)/256 = 10304 blocks exactly.
// ---------------------------------------------------------------------------
__global__ __launch_bounds__(256) void prep_new(
    const float* __restrict__ feature,    // [64][60][512]
    const int*   __restrict__ captions,   // [64][20]
    const float* __restrict__ embedding,  // [32000][512]
    const float* __restrict__ W_ih,       // [2048][1024]
    const float* __restrict__ W_lin,      // [32000][512]
    short* __restrict__ xs,               // [3840][1024] bf16
    short* __restrict__ wih,              // [2048][1024] bf16
    short* __restrict__ wbf,              // [32000][512] bf16
    unsigned* __restrict__ flags)
{
    const int tid = threadIdx.x;
    if (blockIdx.x == 0 && tid < 128) flags[tid] = 0;

    const int NF = 3840 * 64;
    const int NE = 1280 * 64;
    const int NW = 2048 * 128;
    const int NL = 2048000;
    const int idx = blockIdx.x * 256 + tid;

    if (idx < NF) {
        int row = idx >> 6, c8 = (idx & 63) * 8;
        int t = row >> 6, b = row & 63;
        *(int4*)&xs[(size_t)row * 1024 + 512 + c8] =
            ld8_f32_to_bf16(&feature[(size_t)(b * 60 + t) * 512 + c8]);
    } else if (idx < NF + NE) {
        int j = idx - NF;
        int r = j >> 6, c8 = (j & 63) * 8;
        int t = 40 + (r >> 6), b = r & 63;
        int tok = captions[b * 20 + (t - 40)];
        *(int4*)&xs[(size_t)(2560 + r) * 1024 + c8] =
            ld8_f32_to_bf16(&embedding[(size_t)tok * 512 + c8]);
    } else if (idx < NF + NE + NW) {
        int j = idx - NF - NE;
        *(int4*)&wih[(size_t)j * 8] = ld8_f32_to_bf16(&W_ih[(size_t)j * 8]);
    } else if (idx < NF + NE + NW + NL) {
        int j = idx - NF - NE - NW;
        *(int4*)&wbf[(size_t)j * 8] = ld8_f32_to_bf16(&W_lin[(size_t)j * 8]);
    }
}

// ---------------------------------------------------------------------------
// xproj_gemm: Xp[3840][2048] = xs @ wih^T + (b_ih+b_hh), pure bf16 inputs,
// swizzled global_load_lds staging. Enc m-tiles (by<20) start K at 512.
// ---------------------------------------------------------------------------
__global__ __launch_bounds__(256) void xproj_gemm(
    const short* __restrict__ xs,     // [3840][1024] bf16
    const short* __restrict__ wih,    // [2048][1024] bf16
    const float* __restrict__ b_ih,
    const float* __restrict__ b_hh,
    float* __restrict__ Xp)           // [3840][2048]
{
    __shared__ __align__(16) short Al[128 * 64];
    __shared__ __align__(16) short Bl[128 * 64];
    const int tid  = threadIdx.x;
    const int wave = tid >> 6, lane = tid & 63;
    const int quad = lane >> 4, l16 = lane & 15;
    const int m0 = blockIdx.y * 128;
    const int n0 = blockIdx.x * 128;
    const int wm = (wave >> 1) * 64, wn = (wave & 1) * 64;
    const int kstart = (blockIdx.y >= 20) ? 0 : 512;   // enc rows: x[:512]==0

    const char* Ab = (const char*)xs;     // row stride 2048 B
    const char* Wb = (const char*)wih;    // row stride 2048 B
    char* AlB = (char*)Al;
    char* BlB = (char*)Bl;

    f32x4 acc[4][4] = {};

    for (int k0 = kstart; k0 < 1024; k0 += 64) {
#pragma unroll
        for (int p = 0; p < 4; ++p) {
            int row = p * 32 + wave * 8 + (lane >> 3);   // 0..127
            int ss  = ((lane & 7) ^ (row & 7)) << 4;     // swizzled 16B slot
            gload_lds16(Ab + (size_t)(m0 + row) * 2048 + k0 * 2 + ss,
                        AlB + p * 4096 + wave * 1024);
            gload_lds16(Wb + (size_t)(n0 + row) * 2048 + k0 * 2 + ss,
                        BlB + p * 4096 + wave * 1024);
        }
        __syncthreads();
#pragma unroll
        for (int kk = 0; kk < 64; kk += 32) {
            bf16x8 af[4], bg[4];
            const int s_ = (kk >> 3) + quad;
#pragma unroll
            for (int i = 0; i < 4; ++i) {
                int rw = wm + i * 16 + l16;
                af[i] = *(const bf16x8*)&Al[rw * 64 + ((s_ ^ (rw & 7)) << 3)];
            }
#pragma unroll
            for (int jj = 0; jj < 4; ++jj) {
                int rw = wn + jj * 16 + l16;
                bg[jj] = *(const bf16x8*)&Bl[rw * 64 + ((s_ ^ (rw & 7)) << 3)];
            }
#pragma unroll
            for (int i = 0; i < 4; ++i)
#pragma unroll
                for (int jj = 0; jj < 4; ++jj)
                    acc[i][jj] = __builtin_amdgcn_mfma_f32_16x16x32_bf16(
                        af[i], bg[jj], acc[i][jj], 0, 0, 0);
        }
        __syncthreads();
    }

#pragma unroll
    for (int jj = 0; jj < 4; ++jj) {
        int n = n0 + wn + jj * 16 + l16;
        float bv = b_ih[n] + b_hh[n];
#pragma unroll
        for (int i = 0; i < 4; ++i) {
            int mbase = m0 + wm + i * 16 + quad * 4;
#pragma unroll
            for (int r = 0; r < 4; ++r)
                Xp[(size_t)(mbase + r) * 2048 + n] = acc[i][jj][r] + bv;
        }
    }
}

// ---------------------------------------------------------------------------
// prep_old (fallback path only — r9 verbatim): xproj tiles | flags | cvt.
// ---------------------------------------------------------------------------
__global__ __launch_bounds__(256) void prep_old(
    const float* __restrict__ feature,
    const int*   __restrict__ captions,
    const float* __restrict__ embedding,
    const float* __restrict__ W_ih,
    const float* __restrict__ b_ih,
    const float* __restrict__ b_hh,
    float* __restrict__ Xp,
    const float* __restrict__ W_lin,
    short* __restrict__ wbf,
    unsigned* __restrict__ flags)
{
    const int blk = blockIdx.x;
    const int tid = threadIdx.x;

    if (blk == 480) {
        if (tid < 128) flags[tid] = 0;
        return;
    }
    if (blk > 480) {
        if (wbf) {
            int i = (blk - 481) * 256 + tid;
            if (i < 2048000)
                *(int4*)&wbf[(size_t)i * 8] = ld8_f32_to_bf16(&W_lin[(size_t)i * 8]);
        }
        return;
    }

    __shared__ __align__(16) short Al[128 * 72];
    __shared__ __align__(16) short Bl[128 * 72];
    const int wave = tid >> 6, lane = tid & 63;
    const int quad = lane >> 4, l16 = lane & 15;
    const int bx = blk & 15, by = blk >> 4;
    const int m0 = by * 128;
    const int n0 = bx * 128;
    const int wm = (wave >> 1) * 64, wn = (wave & 1) * 64;
    const int sr = tid >> 3;
    const int sc = (tid & 7) * 8;
    const bool dec = (by >= 20);
    const int kstart = dec ? 0 : 512;

    f32x4 acc[4][4] = {};

    for (int k0 = kstart; k0 < 1024; k0 += 64) {
        const int j = k0 + sc;
#pragma unroll
        for (int p = 0; p < 4; ++p) {
            int r = sr + p * 32;
            int row = m0 + r;
            int t = row >> 6, b = row & 63;
            int4 val;
            if (dec && j < 512) {
                int tok = captions[b * 20 + (t - 40)];
                val = ld8_f32_to_bf16(&embedding[(size_t)tok * 512 + j]);
            } else {
                val = ld8_f32_to_bf16(&feature[(size_t)(b * 60 + t) * 512 + (j - 512)]);
            }
            *(int4*)&Al[r * 72 + sc] = val;
            *(int4*)&Bl[r * 72 + sc] = ld8_f32_to_bf16(&W_ih[(size_t)(n0 + r) * 1024 + j]);
        }
        __syncthreads();
#pragma unroll
        for (int kk = 0; kk < 64; kk += 32) {
            bf16x8 af[4], bg[4];
#pragma unroll
            for (int i = 0; i < 4; ++i)
                af[i] = *(const bf16x8*)&Al[(wm + i * 16 + l16) * 72 + kk + quad * 8];
#pragma unroll
            for (int jj = 0; jj < 4; ++jj)
                bg[jj] = *(const bf16x8*)&Bl[(wn + jj * 16 + l16) * 72 + kk + quad * 8];
#pragma unroll
            for (int i = 0; i < 4; ++i)
#pragma unroll
                for (int jj = 0; jj < 4; ++jj)
                    acc[i][jj] = __builtin_amdgcn_mfma_f32_16x16x32_bf16(
                        af[i], bg[jj], acc[i][jj], 0, 0, 0);
        }
        __syncthreads();
    }

#pragma unroll
    for (int jj = 0; jj < 4; ++jj) {
        int n = n0 + wn + jj * 16 + l16;
        float bv = b_ih[n] + b_hh[n];
#pragma unroll
        for (int i = 0; i < 4; ++i) {
            int mbase = m0 + wm + i * 16 + quad * 4;
#pragma unroll
            for (int r = 0; r < 4; ++r)
                Xp[(size_t)(mbase + r) * 2048 + n] = acc[i][jj][r] + bv;
        }
    }
}

// ---------------------------------------------------------------------------
// Standalone GEMM2 (serial fallback): A slice-major bf16; C rows permuted.
// ---------------------------------------------------------------------------
template <bool BF16B>
__global__ __launch_bounds__(256) void gemm_out(
    const short* __restrict__ A,
    const void*  __restrict__ Wv,
    const float* __restrict__ bias,
    float* __restrict__ C,
    int M, int N, int K)
{
    __shared__ __align__(16) short Al[128 * 72];
    __shared__ __align__(16) short Bl[128 * 72];
    const int tid  = threadIdx.x;
    const int wave = tid >> 6, lane = tid & 63;
    const int quad = lane >> 4, l16 = lane & 15;
    const int m0 = blockIdx.y * 128;
    const int n0 = blockIdx.x * 128;
    const int wm = (wave >> 1) * 64, wn = (wave & 1) * 64;
    const int sr = tid >> 3;
    const int sc = (tid & 7) * 8;

    f32x4 acc[4][4] = {};

    for (int k0 = 0; k0 < K; k0 += 64) {
#pragma unroll
        for (int p = 0; p < 4; ++p) {
            int r = sr + p * 32;
            int am = m0 + r;
            am = (am < M) ? am : (M - 1);
            *(int4*)&Al[r * 72 + sc] = *(const int4*)&A[(size_t)am * K + k0 + sc];
            if (BF16B)
                *(int4*)&Bl[r * 72 + sc] =
                    *(const int4*)&((const short*)Wv)[(size_t)(n0 + r) * K + k0 + sc];
            else
                *(int4*)&Bl[r * 72 + sc] =
                    ld8_f32_to_bf16(&((const float*)Wv)[(size_t)(n0 + r) * K + k0 + sc]);
        }
        __syncthreads();
#pragma unroll
        for (int kk = 0; kk < 64; kk += 32) {
            bf16x8 af[4], bg[4];
#pragma unroll
            for (int i = 0; i < 4; ++i)
                af[i] = *(const bf16x8*)&Al[(wm + i * 16 + l16) * 72 + kk + quad * 8];
#pragma unroll
            for (int jj = 0; jj < 4; ++jj)
                bg[jj] = *(const bf16x8*)&Bl[(wn + jj * 16 + l16) * 72 + kk + quad * 8];
#pragma unroll
            for (int i = 0; i < 4; ++i)
#pragma unroll
                for (int jj = 0; jj < 4; ++jj)
                    acc[i][jj] = __builtin_amdgcn_mfma_f32_16x16x32_bf16(
                        af[i], bg[jj], acc[i][jj], 0, 0, 0);
        }
        __syncthreads();
    }

#pragma unroll
    for (int jj = 0; jj < 4; ++jj) {
        int n = n0 + wn + jj * 16 + l16;
        float bv = bias[n];
#pragma unroll
        for (int i = 0; i < 4; ++i) {
            int mbase = m0 + wm + i * 16 + quad * 4;
#pragma unroll
            for (int r = 0; r < 4; ++r) {
                int ar = mbase + r;
                if (ar < M) {
                    int crow = (ar & 63) * 19 + (ar >> 6);
                    C[(size_t)crow * N + n] = acc[i][jj][r] + bv;
                }
            }
        }
    }
}

// ---------------------------------------------------------------------------
// MEGA (verbatim r9/r10, measured 418us): blocks 0..31 LSTM; 32.. consumers.
// ---------------------------------------------------------------------------
__global__ __launch_bounds__(256, 1) void mega(
    const float* __restrict__ Xp,     // [59][64][2048] fp32
    const float* __restrict__ W_hh,   // [2048][512] fp32
    unsigned long long* __restrict__ hbuf,  // [2][64][512] bf16 ping-pong
    unsigned long long* __restrict__ dec_h, // [(t-40)*64+b][512] bf16 as u64
    unsigned* __restrict__ flags,     // [33]: 0..31 per-block, 32 = epoch
    const short* __restrict__ wbf,    // [32000][512] bf16
    const float* __restrict__ b_lin,  // [32000]
    float* __restrict__ out)          // [1216][32000] fp32
{
    __shared__ __align__(16) char smem[67584];   // 66 KB -> 2 blocks/CU
    const int tid  = threadIdx.x;
    const int wave = tid >> 6, lane = tid & 63;
    const int quad = lane >> 4, l16 = lane & 15;

    if (blockIdx.x < LSTM_BLOCKS) {
        short* Wl  = (short*)smem;                 // 64 KB, swizzled
        short* Htb = (short*)(smem + 65536);       // 2 KB
        const int nb = blockIdx.x * 16;
        const int swz = (l16 & 7) << 3;

#pragma unroll
        for (int it = 0; it < 16; ++it) {
            int rr = (tid >> 6) + it * 4;
            int k  = (tid & 63) * 8;
            int s = rr >> 4, col = rr & 15;
            *(int4*)&Wl[(rr * 512 + k) ^ ((rr & 7) << 3)] =
                ld8_f32_to_bf16(&W_hh[(size_t)(s * 512 + nb + col) * 512 + k]);
        }
        float creg[4] = {0.f, 0.f, 0.f, 0.f};

        const int n = nb + l16;
        float xg[4][4];
#pragma unroll
        for (int r = 0; r < 4; ++r) {
            const float* xr = Xp + (size_t)(wave * 16 + quad * 4 + r) * 2048;
            xg[r][0] = xr[n];
            xg[r][1] = xr[512 + n];
            xg[r][2] = xr[1024 + n];
            xg[r][3] = xr[1536 + n];
        }
        __syncthreads();

        for (int t = 0; t < 59; ++t) {
            f32x4 acc[4] = {};
            if (t > 0) {
                const unsigned long long* hrow =
                    hbuf + ((size_t)((t & 1) ^ 1) << 13)
                         + (size_t)(wave * 16 + l16) * 128 + quad * 2;
                union { unsigned long long q[2]; bf16x8 v; } hu[16];
#pragma unroll
                for (int kk = 0; kk < 16; ++kk) {
                    hu[kk].q[0] = __hip_atomic_load(&hrow[kk * 8],
                                     __ATOMIC_RELAXED, __HIP_MEMORY_SCOPE_AGENT);
                    hu[kk].q[1] = __hip_atomic_load(&hrow[kk * 8 + 1],
                                     __ATOMIC_RELAXED, __HIP_MEMORY_SCOPE_AGENT);
                }
                __builtin_amdgcn_sched_barrier(0);
#pragma unroll
                for (int kk = 0; kk < 16; ++kk) {
#pragma unroll
                    for (int s = 0; s < 4; ++s) {
                        bf16x8 bg = *(const bf16x8*)
                            &Wl[((s * 16 + l16) * 512 + kk * 32 + quad * 8) ^ swz];
                        acc[s] = __builtin_amdgcn_mfma_f32_16x16x32_bf16(
                            hu[kk].v, bg, acc[s], 0, 0, 0);
                    }
                }
            }
#pragma unroll
            for (int r = 0; r < 4; ++r) {
                float iv = acc[0][r] + xg[r][0];
                float fv = acc[1][r] + xg[r][1];
                float gv = acc[2][r] + xg[r][2];
                float ov = acc[3][r] + xg[r][3];
                float cn = sig_fast(fv) * creg[r] + sig_fast(iv) * tanh_fast(gv);
                float hn = sig_fast(ov) * tanh_fast(cn);
                creg[r] = cn;
                Htb[(wave << 8) + ((quad * 4 + r) << 4) + l16] = f2bf(hn);
            }
            asm volatile("s_waitcnt lgkmcnt(0)" ::: "memory");
            unsigned long long* hout64 = hbuf + ((size_t)(t & 1) << 13);
            {
                int row = lane >> 2, qp = lane & 3;
                unsigned long long v =
                    *(const unsigned long long*)&Htb[(wave << 8) + (row << 4) + qp * 4];
                int m = wave * 16 + row;
                __hip_atomic_store(&hout64[m * 128 + (nb >> 2) + qp], v,
                                   __ATOMIC_RELAXED, __HIP_MEMORY_SCOPE_AGENT);
                if (t >= 40)
                    __hip_atomic_store(
                        &dec_h[(size_t)((t - 40) * 64 + m) * 128 + (nb >> 2) + qp], v,
                        __ATOMIC_RELAXED, __HIP_MEMORY_SCOPE_AGENT);
            }
            if (t < 58) {
                float xn_[4][4];
                const float* xt = Xp + (size_t)(t + 1) * 131072;
#pragma unroll
                for (int r = 0; r < 4; ++r) {
                    const float* xr = xt + (size_t)(wave * 16 + quad * 4 + r) * 2048;
                    xn_[r][0] = xr[n];
                    xn_[r][1] = xr[512 + n];
                    xn_[r][2] = xr[1024 + n];
                    xn_[r][3] = xr[1536 + n];
                }
                __syncthreads();   // drains vmcnt(0): h+dec_h at coherence pt
                if (tid == 0)
                    __hip_atomic_store(&flags[blockIdx.x], (unsigned)(t + 1),
                                       __ATOMIC_RELAXED, __HIP_MEMORY_SCOPE_AGENT);
                if (tid < LSTM_BLOCKS) {
                    int guard = 0;
                    while (__hip_atomic_load(&flags[tid], __ATOMIC_RELAXED,
                                             __HIP_MEMORY_SCOPE_AGENT) < (unsigned)(t + 1)
                           && guard < (1 << 16)) {
                        __builtin_amdgcn_s_sleep(1);
                        ++guard;
                    }
                }
                __syncthreads();
                if (blockIdx.x == 0 && tid == 0)
                    __hip_atomic_store(&flags[32], (unsigned)(t + 1),
                                       __ATOMIC_RELAXED, __HIP_MEMORY_SCOPE_AGENT);
#pragma unroll
                for (int r = 0; r < 4; ++r)
#pragma unroll
                    for (int g = 0; g < 4; ++g)
                        xg[r][g] = xn_[r][g];
            }
        }
        __syncthreads();           // drains t=58 dec_h/h stores
        if (tid == 0)
            __hip_atomic_store(&flags[blockIdx.x], 59u,
                               __ATOMIC_RELAXED, __HIP_MEMORY_SCOPE_AGENT);
        if (blockIdx.x == 0) {
            if (tid < LSTM_BLOCKS) {
                int guard = 0;
                while (__hip_atomic_load(&flags[tid], __ATOMIC_RELAXED,
                                         __HIP_MEMORY_SCOPE_AGENT) < 59u
                       && guard < (1 << 16)) {
                    __builtin_amdgcn_s_sleep(1);
                    ++guard;
                }
            }
            __syncthreads();
            if (tid == 0)
                __hip_atomic_store(&flags[32], 59u,
                                   __ATOMIC_RELAXED, __HIP_MEMORY_SCOPE_AGENT);
        }
        return;
    }

    // ================= consumer v2: one 128x128 tile of out ================
    short* Al = (short*)smem;                      // 128 x 72 padded (A)
    short* Bl = (short*)(smem + 18432);            // 128 x 64 swizzled (B)
    const int cid = blockIdx.x - LSTM_BLOCKS;
    const int n0 = (cid % 250) * 128;
    const int mt = cid / 250;
    const int m0 = mt * 128;
    const int M = 1216;
    const int wm = (wave >> 1) * 64, wn = (wave & 1) * 64;
    const int sr = tid >> 3;
    const int sc = (tid & 7) * 8;
    int maxa = m0 + 127; maxa = (maxa < M - 1) ? maxa : (M - 1);
    const unsigned v = 41u + (unsigned)(maxa >> 6);

    if (tid == 0) {
        int guard = 0;
        while (__hip_atomic_load(&flags[32], __ATOMIC_RELAXED,
                                 __HIP_MEMORY_SCOPE_AGENT) < v
               && guard < (1 << 14)) {
            __builtin_amdgcn_s_sleep(64);
            ++guard;
        }
    }
    __syncthreads();

    f32x4 acc[4][4] = {};
    const char* Wb = (const char*)wbf;
    char* BlB = (char*)Bl;

    for (int k0 = 0; k0 < 512; k0 += 64) {
#pragma unroll
        for (int p = 0; p < 4; ++p) {
            int r = sr + p * 32;
            int ar = m0 + r; ar = (ar < M) ? ar : (M - 1);
            size_t qi = (size_t)ar * 128 + ((k0 + sc) >> 2);
            union { unsigned long long q[2]; int4 v4; } u;
            u.q[0] = __hip_atomic_load(&dec_h[qi],
                         __ATOMIC_RELAXED, __HIP_MEMORY_SCOPE_AGENT);
            u.q[1] = __hip_atomic_load(&dec_h[qi + 1],
                         __ATOMIC_RELAXED, __HIP_MEMORY_SCOPE_AGENT);
            *(int4*)&Al[r * 72 + sc] = u.v4;
        }
#pragma unroll
        for (int p = 0; p < 4; ++p) {
            int row = p * 32 + wave * 8 + (lane >> 3);
            int ss  = ((lane & 7) ^ (row & 7)) << 4;
            gload_lds16(Wb + (size_t)(n0 + row) * 1024 + k0 * 2 + ss,
                        BlB + p * 4096 + wave * 1024);
        }
        __syncthreads();
#pragma unroll
        for (int kk = 0; kk < 64; kk += 32) {
            bf16x8 af[4], bg[4];
            const int s_ = (kk >> 3) + quad;
#pragma unroll
            for (int i = 0; i < 4; ++i)
                af[i] = *(const bf16x8*)&Al[(wm + i * 16 + l16) * 72 + kk + quad * 8];
#pragma unroll
            for (int jj = 0; jj < 4; ++jj) {
                int rw = wn + jj * 16 + l16;
                bg[jj] = *(const bf16x8*)&Bl[rw * 64 + ((s_ ^ (rw & 7)) << 3)];
            }
#pragma unroll
            for (int i = 0; i < 4; ++i)
#pragma unroll
                for (int jj = 0; jj < 4; ++jj)
                    acc[i][jj] = __builtin_amdgcn_mfma_f32_16x16x32_bf16(
                        af[i], bg[jj], acc[i][jj], 0, 0, 0);
        }
        __syncthreads();
    }

#pragma unroll
    for (int jj = 0; jj < 4; ++jj) {
        int n = n0 + wn + jj * 16 + l16;
        float bv = b_lin[n];
#pragma unroll
        for (int i = 0; i < 4; ++i) {
            int mbase = m0 + wm + i * 16 + quad * 4;
#pragma unroll
            for (int r = 0; r < 4; ++r) {
                int ar = mbase + r;
                if (ar < M) {
                    int crow = (ar & 63) * 19 + (ar >> 6);   // b*19 + dec
                    out[(size_t)crow * 32000 + n] = acc[i][jj][r] + bv;
                }
            }
        }
    }
}

// ---------------------------------------------------------------------------
extern "C" void kernel_launch(void* const* d_in, const int* in_sizes, int n_in,
                              void* d_out, int out_size, void* d_ws, size_t ws_size,
                              hipStream_t stream)
{
    (void)in_sizes; (void)n_in; (void)out_size;
    const float* feature   = (const float*)d_in[0];
    const int*   captions  = (const int*)d_in[1];
    const float* embedding = (const float*)d_in[2];
    const float* W_ih      = (const float*)d_in[3];
    const float* W_hh      = (const float*)d_in[4];
    const float* b_ih      = (const float*)d_in[5];
    const float* b_hh      = (const float*)d_in[6];
    const float* W_lin     = (const float*)d_in[7];
    const float* b_lin     = (const float*)d_in[8];
    float* out = (float*)d_out;

    // ws layout
    char* ws = (char*)d_ws;
    unsigned long long* hbuf = (unsigned long long*)(ws);          // 131,072 B
    unsigned long long* dech = (unsigned long long*)(ws + 131072); // 1,245,184 B
    unsigned* flags = (unsigned*)(ws + 1376256);                   // 512 B
    short*    wbf   = (short*)(ws + 1376768);                      // 32,768,000 B
    float*    xpws  = (float*)(ws + 34144768);                     // 31,457,280 B
    const bool big  = ws_size >= (size_t)34144768;
    const bool bigx = ws_size >= (size_t)34144768 + 31457280;

    if (bigx) {
        // xs/wih in d_out's tail: dead before consumers write out.
        short* xs  = (short*)((char*)d_out + 143589376);   // 7,864,320 B
        short* wih = (short*)((char*)d_out + 151453696);   // 4,194,304 B
        float* Xp  = xpws;

        // one chunk per thread: (NF+NE+NW+NL)/256 = 10304 blocks exactly
        prep_new<<<10304, 256, 0, stream>>>(
            feature, captions, embedding, W_ih, W_lin, xs, wih, wbf, flags);

        xproj_gemm<<<dim3(16, 30), 256, 0, stream>>>(xs, wih, b_ih, b_hh, Xp);

        mega<<<dim3(LSTM_BLOCKS + 2500), 256, 0, stream>>>(
            Xp, W_hh, hbuf, dech, flags, wbf, b_lin, out);
    } else {
        // fallback: r9 serial pipeline
        float* Xp = (float*)d_out;
        prep_old<<<dim3(big ? 8481 : 481), 256, 0, stream>>>(
            feature, captions, embedding, W_ih, b_ih, b_hh, Xp,
            W_lin, big ? wbf : (short*)nullptr, flags);
        mega<<<dim3(LSTM_BLOCKS), 256, 0, stream>>>(
            Xp, W_hh, hbuf, dech, flags, (const short*)nullptr, b_lin, out);
        if (big)
            gemm_out<true><<<dim3(250, 10), 256, 0, stream>>>(
                (const short*)dech, wbf, b_lin, out, 1216, 32000, 512);
        else
            gemm_out<false><<<dim3(250, 10), 256, 0, stream>>>(
                (const short*)dech, W_lin, b_lin, out, 1216, 32000, 512);
    }
}